// Round 1
// baseline (133.484 us; speedup 1.0000x reference)
//
#include <hip/hip_runtime.h>

// Problem constants (fixed by setup_inputs)
#define BATCHES   8
#define N_PER     8192
#define M_PER     2048
#define C_FEAT    32
#define KNN       32
#define R2        0.04f            // 0.2^2
#define M_TOT     (BATCHES * M_PER)            // 16384
#define FEAT_OUT  (3 + C_FEAT)                 // 35
#define OUT_FEAT_SZ ((size_t)M_TOT * FEAT_OUT * KNN)   // 18,350,080 floats

// One block = 256 threads = 4 waves. Each wave handles 2 queries:
//   phase 1 (ball query) runs full-wave per query (sequentially for h=0,1),
//   phase 2 (gather+write) runs half-wave per query (lane&31 = slot).
__global__ __launch_bounds__(256) void sqag_kernel(
    const float* __restrict__ xyz,        // (B*N_PER, 3)
    const float* __restrict__ new_xyz,    // (B*M_PER, 3)
    const float* __restrict__ features,   // (B*N_PER, C_FEAT)
    float* __restrict__ out)              // feats (M,35,K) then idx (M,K) as float
{
    __shared__ int sidx_all[4][2][KNN];

    const int wave       = threadIdx.x >> 6;
    const int lane       = threadIdx.x & 63;
    const int wave_global = blockIdx.x * 4 + wave;

    int cnts[2];

    #pragma unroll
    for (int h = 0; h < 2; ++h) {
        const int q    = wave_global * 2 + h;
        const int b    = q >> 11;                 // / M_PER
        const int base = b * N_PER;

        const float px = new_xyz[q * 3 + 0];
        const float py = new_xyz[q * 3 + 1];
        const float pz = new_xyz[q * 3 + 2];

        int cnt = 0;
        int first = 0;   // first in-range local index (wave-uniform once found)

        for (int cb = 0; cb < N_PER; cb += 64) {
            const int i = cb + lane;
            const float x = xyz[(size_t)(base + i) * 3 + 0];
            const float y = xyz[(size_t)(base + i) * 3 + 1];
            const float z = xyz[(size_t)(base + i) * 3 + 2];
            const float dx = px - x;
            const float dy = py - y;
            const float dz = pz - z;
            // match numpy: ((dx*dx + dy*dy) + dz*dz), no FMA contraction
            const float d2 = __fadd_rn(__fadd_rn(__fmul_rn(dx, dx),
                                                 __fmul_rn(dy, dy)),
                                       __fmul_rn(dz, dz));
            const bool in = d2 < R2;
            const unsigned long long m = __ballot(in);
            if (m) {
                if (cnt == 0) first = cb + (__ffsll((long long)m) - 1);
                if (in) {
                    const int rank = cnt +
                        __popcll(m & ((1ull << lane) - 1ull));
                    if (rank < KNN) sidx_all[wave][h][rank] = i;
                }
                cnt += __popcll(m);
                if (cnt >= KNN) break;   // wave-uniform
            }
        }

        // pad slots [cnt, KNN) with first hit (or 0 if empty)
        const int pad = (cnt == 0) ? 0 : first;
        if (lane >= cnt && lane < KNN) sidx_all[wave][h][lane] = pad;

        cnts[h] = cnt;
    }

    __syncthreads();   // order LDS writes before phase-2 reads (all threads reach)

    // ---- phase 2: half-wave per query ----
    const int h   = lane >> 5;            // 0 or 1
    const int k   = lane & 31;            // slot
    const int q   = wave_global * 2 + h;
    const int b   = q >> 11;
    const int base = b * N_PER;

    const bool empty = (cnts[h] == 0);
    const float zf   = empty ? 0.0f : 1.0f;

    const int li = sidx_all[wave][h][k];  // local index within batch
    const int gi = base + li;

    const float px = new_xyz[q * 3 + 0];
    const float py = new_xyz[q * 3 + 1];
    const float pz = new_xyz[q * 3 + 2];

    const float gx = xyz[(size_t)gi * 3 + 0] - px;
    const float gy = xyz[(size_t)gi * 3 + 1] - py;
    const float gz = xyz[(size_t)gi * 3 + 2] - pz;

    float* o = out + (size_t)q * (FEAT_OUT * KNN);
    o[0 * KNN + k] = zf * gx;
    o[1 * KNN + k] = zf * gy;
    o[2 * KNN + k] = zf * gz;

    const float4* f = (const float4*)(features + (size_t)gi * C_FEAT);
    #pragma unroll
    for (int j4 = 0; j4 < C_FEAT / 4; ++j4) {
        const float4 v = f[j4];
        o[(3 + j4 * 4 + 0) * KNN + k] = zf * v.x;
        o[(3 + j4 * 4 + 1) * KNN + k] = zf * v.y;
        o[(3 + j4 * 4 + 2) * KNN + k] = zf * v.z;
        o[(3 + j4 * 4 + 3) * KNN + k] = zf * v.w;
    }

    // idx output, written as float (whole d_out read as float32 by harness)
    out[OUT_FEAT_SZ + (size_t)q * KNN + k] = (float)li;
}

extern "C" void kernel_launch(void* const* d_in, const int* in_sizes, int n_in,
                              void* d_out, int out_size, void* d_ws, size_t ws_size,
                              hipStream_t stream) {
    const float* xyz      = (const float*)d_in[0];
    // d_in[1] = xyz_batch_cnt (constant 8192 each) — unused
    const float* new_xyz  = (const float*)d_in[2];
    // d_in[3] = new_xyz_batch_cnt (constant 2048 each) — unused
    const float* features = (const float*)d_in[4];
    float* out = (float*)d_out;

    // 16384 queries, 2 per wave, 4 waves per block -> 2048 blocks
    const int blocks = (M_TOT / 2 + 3) / 4;   // 2048
    sqag_kernel<<<blocks, 256, 0, stream>>>(xyz, new_xyz, features, out);
}